// Round 16
// baseline (303.552 us; speedup 1.0000x reference)
//
#include <hip/hip_runtime.h>
#include <hip/hip_fp16.h>
#include <cstdint>

#define HIDDEN 1024
#define ATTN   512
#define NB     8
#define SEQ    2048
#define MROWS  (NB*SEQ)   // 16384

typedef _Float16 f16x8 __attribute__((ext_vector_type(8)));
typedef _Float16 f16x4 __attribute__((ext_vector_type(4)));
typedef float    f32x4 __attribute__((ext_vector_type(4)));

// Fragment-major tiled layout for all fp16 MFMA operands (q/k/vT/P16):
//   addr(r, c) = (r>>4)*(16*C) + (c>>5)*512 + (r&15)*32 + (c&31)   [halfs]
// => a wave's 16x32 fragment is one contiguous 1KB block (single-segment load).

__device__ __forceinline__ float tanh_fast(float x){
  float e = __expf(2.0f*x);
  return 1.0f - 2.0f/(e + 1.0f);
}

__device__ __forceinline__ void gload16(const void* g, void* l){
  __builtin_amdgcn_global_load_lds((const __attribute__((address_space(1))) void*)g,
                                   (__attribute__((address_space(3))) void*)l, 16, 0, 0);
}

// ---------------- K0a: cast inputs f32 -> fp16 ----------------
__global__ __launch_bounds__(256) void k_cast_x(const float* __restrict__ x, __half* __restrict__ xh){
  size_t i = (size_t)blockIdx.x*256 + threadIdx.x;
  const float4* src = reinterpret_cast<const float4*>(x) + i*2;
  float4 a = src[0], b = src[1];
  f16x8 h;
  h[0]=(_Float16)a.x; h[1]=(_Float16)a.y; h[2]=(_Float16)a.z; h[3]=(_Float16)a.w;
  h[4]=(_Float16)b.x; h[5]=(_Float16)b.y; h[6]=(_Float16)b.z; h[7]=(_Float16)b.w;
  reinterpret_cast<f16x8*>(xh)[i] = h;
}

// ---------------- K0b: W[1024][512] f32 -> WhT[512][1024] fp16 (x3) ----------------
__global__ __launch_bounds__(256) void k_transpose_w(const float* __restrict__ Wq, const float* __restrict__ Wk,
                                                     const float* __restrict__ Wv, __half* __restrict__ whT){
  __shared__ float lds[32][33];
  int which = blockIdx.y;
  const float* W = which==0 ? Wq : (which==1 ? Wk : Wv);
  int tr = blockIdx.x >> 4;
  int tc = blockIdx.x & 15;
  int t = threadIdx.x;
  {
    int r = t >> 3, c4 = (t & 7)*4;
    float4 v = *reinterpret_cast<const float4*>(W + (size_t)(tr*32 + r)*ATTN + tc*32 + c4);
    lds[r][c4+0]=v.x; lds[r][c4+1]=v.y; lds[r][c4+2]=v.z; lds[r][c4+3]=v.w;
  }
  __syncthreads();
  {
    int n = t >> 3, k4 = (t & 7)*4;
    ushort4 u;
    u.x = __half_as_ushort(__float2half(lds[k4+0][n]));
    u.y = __half_as_ushort(__float2half(lds[k4+1][n]));
    u.z = __half_as_ushort(__float2half(lds[k4+2][n]));
    u.w = __half_as_ushort(__float2half(lds[k4+3][n]));
    *reinterpret_cast<ushort4*>(whT + (size_t)which*ATTN*HIDDEN + (size_t)(tc*32 + n)*HIDDEN + tr*32 + k4) = u;
  }
}

// ---------------- K1: fused QKV projection ----------------
// q/k outputs fragment-tiled; v written DIRECTLY in vT-tiled layout.
__global__ __launch_bounds__(256,3) void k_proj(const __half* __restrict__ xh, const __half* __restrict__ whT,
                                                const float* __restrict__ bq, const float* __restrict__ bk,
                                                const float* __restrict__ bv,
                                                __half* __restrict__ qh, __half* __restrict__ kh, __half* __restrict__ vT){
  __shared__ __align__(16) _Float16 lA[128*64];   // 16 KB
  __shared__ __align__(16) _Float16 lB[128*64];   // 16 KB
  int nt = blockIdx.x;             // 0..11 : which = nt>>2, 128-col slab = nt&3
  int m0 = blockIdx.y * 128;
  int which = nt >> 2;
  int ncol0 = (nt & 3) * 128;
  int t = threadIdx.x;
  int w = t >> 6, lane = t & 63;
  int lrow = lane & 15, lk = lane >> 4;
  int wm = w >> 1, wn = w & 1;

  int rr = lane >> 3;
  int ss = (lane & 7) ^ rr;
  const __half* Abase = xh + (size_t)(m0 + w*32 + rr)*HIDDEN + ss*8;
  const __half* Bbase = whT + (size_t)which*ATTN*HIDDEN + (size_t)(ncol0 + w*32 + rr)*HIDDEN + ss*8;
  _Float16* lAw = &lA[(w*32)*64];
  _Float16* lBw = &lB[(w*32)*64];

  f32x4 acc[4][4];
  #pragma unroll
  for (int i=0;i<4;i++)
    #pragma unroll
    for (int j=0;j<4;j++) acc[i][j] = f32x4{0.f,0.f,0.f,0.f};

  for (int k0 = 0; k0 < HIDDEN; k0 += 64){
    __syncthreads();
    #pragma unroll
    for (int c=0; c<4; c++){
      gload16(Abase + (size_t)c*8*HIDDEN + k0, &lAw[c*8*64]);
      gload16(Bbase + (size_t)c*8*HIDDEN + k0, &lBw[c*8*64]);
    }
    __syncthreads();
    #pragma unroll
    for (int u=0; u<2; u++){
      f16x8 af[4], bf[4];
      #pragma unroll
      for (int fm=0; fm<4; fm++){
        int row = wm*64 + fm*16 + lrow;
        af[fm] = *(const f16x8*)&lA[row*64 + (((u*4 + lk) ^ (row & 7))*8)];
      }
      #pragma unroll
      for (int fn=0; fn<4; fn++){
        int row = wn*64 + fn*16 + lrow;
        bf[fn] = *(const f16x8*)&lB[row*64 + (((u*4 + lk) ^ (row & 7))*8)];
      }
      #pragma unroll
      for (int fm=0; fm<4; fm++)
        #pragma unroll
        for (int fn=0; fn<4; fn++)
          acc[fm][fn] = __builtin_amdgcn_mfma_f32_16x16x32_f16(af[fm], bf[fn], acc[fm][fn], 0,0,0);
    }
  }

  const float* bias = which==0 ? bq : (which==1 ? bk : bv);
  if (which < 2){
    __half* dst = which==0 ? qh : kh;
    int rt_base = (m0 >> 4) + wm*4;          // + fm
    int at_base = (ncol0 >> 5) + wn*2;       // + (fn>>1)
    #pragma unroll
    for (int fn=0; fn<4; fn++){
      int col = ncol0 + wn*64 + fn*16 + lrow;
      float bb = bias[col];
      int at = at_base + (fn >> 1);
      int asub = (fn & 1)*16 + lrow;
      #pragma unroll
      for (int fm=0; fm<4; fm++){
        size_t tbase = (size_t)(rt_base + fm)*8192 + (size_t)at*512 + asub;
        #pragma unroll
        for (int mi=0; mi<4; mi++)
          dst[tbase + (lk*4 + mi)*32] = __float2half(tanh_fast(acc[fm][fn][mi] + bb));
      }
    }
  } else {
    __half* vb = vT + (size_t)(m0 >> 11)*ATTN*SEQ;   // batch = m0/2048
    int jb0 = (m0 & 2047) + wm*64;                   // + fm*16
    int at0 = (ncol0 >> 4) + wn*4;                   // + fn
    #pragma unroll
    for (int fn=0; fn<4; fn++){
      int col = ncol0 + wn*64 + fn*16 + lrow;
      float bb = bias[col];
      #pragma unroll
      for (int fm=0; fm<4; fm++){
        int jb = jb0 + fm*16;
        f16x4 h;
        #pragma unroll
        for (int mi=0; mi<4; mi++) h[mi] = (_Float16)tanh_fast(acc[fm][fn][mi] + bb);
        *(f16x4*)(vb + (size_t)(at0 + fn)*32768 + (size_t)(jb >> 5)*512 + lrow*32 + (jb & 16) + lk*4) = h;
      }
    }
  }
}

// ---------------- K2new: E = exp(QK^T * scale) UNNORMALIZED -> p16 (tiled) ----------------
// LDS-staged GEMM: 256 blocks (1/CU), 512 thr. Block: 64 q-rows x 2048 keys.
// q (64 KB) staged once; kh staged 32 KB per dim-slice via global_load_lds.
__global__ __launch_bounds__(512,2) void k_scoresE(const __half* __restrict__ qh, const __half* __restrict__ kh,
                                                   __half* __restrict__ p16){
  __shared__ __align__(16) _Float16 qlds[4*16*512];    // 64 KB: chunk c = (qf*16+it)
  __shared__ __align__(16) _Float16 khlds[32*512];     // 32 KB: 32 key-tile chunks x 512 halfs
  int bid = blockIdx.x;
  int b  = bid & 7;            // XCD pin: batch's kh slice (2 MB) resident in one XCD L2
  int i0 = (bid >> 3) * 64;
  int t = threadIdx.x;
  int w = t >> 6, lane = t & 63;
  int lrow = lane & 15, lk = lane >> 4;

  const __half* qsrc = qh + (size_t)((b*SEQ + i0) >> 4)*8192;   // 64 KB contiguous (tiled)
  const __half* ksrc = kh + (size_t)b*SEQ*ATTN;                 // batch base (tiled)
  __half* pb = p16 + (size_t)b*SEQ*SEQ;

  #pragma unroll
  for (int r=0; r<8; r++){
    int chunk = r*8 + w;
    gload16(qsrc + (size_t)chunk*512 + lane*8, &qlds[chunk*512]);
  }

  const float scale = 0.044194173824159216f;   // 1/sqrt(512)
  for (int ko = 0; ko < 4; ko++){              // key-outer: keys [ko*512, ko*512+512)
    f32x4 acc[4][4];                            // [qf][fn]
    #pragma unroll
    for (int i=0;i<4;i++)
      #pragma unroll
      for (int j=0;j<4;j++) acc[i][j] = f32x4{0.f,0.f,0.f,0.f};

    for (int it = 0; it < 16; it++){           // dim-slice [it*32, it*32+32)
      __syncthreads();
      #pragma unroll
      for (int j=0; j<4; j++){
        int c = w*4 + j;
        gload16(ksrc + (size_t)(ko*32 + c)*8192 + it*512 + lane*8, &khlds[c*512]);
      }
      __syncthreads();
      f16x8 kf[4], qf[4];
      #pragma unroll
      for (int j=0;j<4;j++) kf[j] = *(const f16x8*)&khlds[(w*4+j)*512 + lrow*32 + lk*8];
      #pragma unroll
      for (int j=0;j<4;j++) qf[j] = *(const f16x8*)&qlds[(j*16 + it)*512 + lrow*32 + lk*8];
      #pragma unroll
      for (int fn=0; fn<4; fn++)
        #pragma unroll
        for (int qi=0; qi<4; qi++)
          acc[qi][fn] = __builtin_amdgcn_mfma_f32_16x16x32_f16(kf[fn], qf[qi], acc[qi][fn], 0,0,0);
    }

    #pragma unroll
    for (int qi=0; qi<4; qi++){
      size_t tq = (size_t)((i0 >> 4) + qi)*32768;
      #pragma unroll
      for (int fn=0; fn<4; fn++){
        f16x4 h;
        #pragma unroll
        for (int mi=0; mi<4; mi++) h[mi] = (_Float16)__expf(acc[qi][fn][mi]*scale);
        *(f16x4*)&pb[tq + (size_t)(ko*16 + w*2 + (fn>>1))*512 + lrow*32 + (fn&1)*16 + lk*4] = h;
      }
    }
  }
}

// ---------------- K2 fallback: scores + no-max softmax (normalized f32 probs) ----------------
__global__ __launch_bounds__(1024,4) void k_scores(const __half* __restrict__ qh, const __half* __restrict__ kh,
                                                   float* __restrict__ probs){
  __shared__ float red[16][32];
  int bid = blockIdx.x;
  int b  = bid & 7;
  int i0 = (bid >> 3) * 32;
  int t = threadIdx.x;
  int w = t >> 6, lane = t & 63;
  int lrow = lane & 15, lk = lane >> 4;
  int loff = lrow*32 + lk*8;

  const __half* kbase = kh + (size_t)((b*SEQ + w*128) >> 4)*8192 + loff;
  const __half* qbase = qh + (size_t)((b*SEQ + i0) >> 4)*8192 + loff;

  f32x4 acc[2][8];
  #pragma unroll
  for (int i=0;i<2;i++)
    #pragma unroll
    for (int j=0;j<8;j++) acc[i][j] = f32x4{0.f,0.f,0.f,0.f};

  for (int it = 0; it < 16; it++){
    f16x8 aq0 = *(const f16x8*)(qbase + it*512);
    f16x8 aq1 = *(const f16x8*)(qbase + 8192 + it*512);
    #pragma unroll
    for (int fn=0; fn<8; fn++){
      f16x8 kf = *(const f16x8*)(kbase + (size_t)fn*8192 + it*512);
      acc[0][fn] = __builtin_amdgcn_mfma_f32_16x16x32_f16(kf, aq0, acc[0][fn], 0,0,0);
      acc[1][fn] = __builtin_amdgcn_mfma_f32_16x16x32_f16(kf, aq1, acc[1][fn], 0,0,0);
    }
  }

  const float scale = 0.044194173824159216f;
  float sm[2];
  #pragma unroll
  for (int nf=0;nf<2;nf++){
    float s = 0.f;
    #pragma unroll
    for (int fn=0;fn<8;fn++)
      #pragma unroll
      for (int mi=0;mi<4;mi++){
        float e = __expf(acc[nf][fn][mi] * scale);
        acc[nf][fn][mi] = e;
        s += e;
      }
    s += __shfl_xor(s, 16);
    s += __shfl_xor(s, 32);
    sm[nf] = s;
  }
  if (lane < 16){ red[w][lane] = sm[0]; red[w][16 + lane] = sm[1]; }
  __syncthreads();
  float inv[2];
  #pragma unroll
  for (int nf=0;nf<2;nf++){
    float tot = 0.f;
    #pragma unroll
    for (int ww=0; ww<16; ww++) tot += red[ww][nf*16 + lrow];
    inv[nf] = 1.0f / tot;
  }
  #pragma unroll
  for (int nf=0;nf<2;nf++){
    f32x4 iv = {inv[nf], inv[nf], inv[nf], inv[nf]};
    #pragma unroll
    for (int fn=0;fn<8;fn++){
      f32x4 v = acc[nf][fn] * iv;
      size_t rowoff = (size_t)(i0 + nf*16 + lrow)*SEQ + w*128 + lk*4;
      *(f32x4*)(probs + (size_t)b*SEQ*SEQ + rowoff + fn*16) = v;
    }
  }
}

// ---------------- K3main: context + probs from UNNORMALIZED E, col-split ----------------
// 512 blocks (2/CU), 512 thr (8 waves). Block: 64 q-rows x 256 cols (ch = col half);
// wave w: cols [ch*256 + w*32, +32), acc[4][2]. Both ch-halves of (b,i0) share the XCD
// (bid and bid+8 -> same bid&7) so p16 frags are L2-shared. rsum computed redundantly;
// probs expansion only on ch==0 blocks.
__global__ __launch_bounds__(512,4) void k_pv_p16(const __half* __restrict__ p16, const __half* __restrict__ vT,
                                                  float* __restrict__ probs, float* __restrict__ out0){
  __shared__ float partial[8][64];
  __shared__ float rsum[64];
  int bid = blockIdx.x;
  int b  = bid & 7;            // XCD pin
  int j  = bid >> 3;           // 0..63
  int i0 = (j >> 1) * 64;
  int ch = j & 1;              // column half: cols [ch*256, ch*256+256)
  int t = threadIdx.x;
  int w = t >> 6, lane = t & 63;
  int lrow = lane & 15, lk = lane >> 4;
  int loff = lrow*32 + lk*8;

  const __half* pbase = p16 + (size_t)b*SEQ*SEQ + (size_t)(i0 >> 4)*32768 + loff;       // + nf*32768 + kt*512
  const __half* vbase = vT + (size_t)b*ATTN*SEQ + (size_t)(ch*16 + w*2)*32768 + loff;   // + cf*32768 + kt*512

  f32x4 acc[4][2];
  #pragma unroll
  for (int i=0;i<4;i++)
    #pragma unroll
    for (int jj=0;jj<2;jj++) acc[i][jj] = f32x4{0.f,0.f,0.f,0.f};
  float esum[4] = {0.f,0.f,0.f,0.f};

  for (int kt = 0; kt < 64; kt++){
    f16x8 pa[4];
    #pragma unroll
    for (int nf=0; nf<4; nf++)
      pa[nf] = *(const f16x8*)(pbase + (size_t)nf*32768 + kt*512);
    if ((kt >> 3) == w){       // wave-uniform: this wave sums these key-tiles
      #pragma unroll
      for (int nf=0; nf<4; nf++){
        float s = 0.f;
        #pragma unroll
        for (int jj=0; jj<8; jj++) s += (float)pa[nf][jj];
        esum[nf] += s;
      }
    }
    #pragma unroll
    for (int cf=0; cf<2; cf++){
      f16x8 bv8 = *(const f16x8*)(vbase + (size_t)cf*32768 + kt*512);
      #pragma unroll
      for (int nf=0; nf<4; nf++)
        acc[nf][cf] = __builtin_amdgcn_mfma_f32_16x16x32_f16(pa[nf], bv8, acc[nf][cf], 0,0,0);
    }
  }

  // row sums: butterfly over lk lanes, then cross-wave LDS reduce
  #pragma unroll
  for (int nf=0; nf<4; nf++){
    esum[nf] += __shfl_xor(esum[nf], 16);
    esum[nf] += __shfl_xor(esum[nf], 32);
  }
  if (lane < 16){
    #pragma unroll
    for (int nf=0; nf<4; nf++) partial[w][nf*16 + lane] = esum[nf];
  }
  __syncthreads();
  if (t < 64){
    float s = 0.f;
    #pragma unroll
    for (int ww=0; ww<8; ww++) s += partial[ww][t];
    rsum[t] = s;
  }
  __syncthreads();

  // out0 = tanh(context * inv)
  float* dst = out0 + ((size_t)b*SEQ + i0)*ATTN + ch*256 + w*32;
  #pragma unroll
  for (int nf=0; nf<4; nf++)
    #pragma unroll
    for (int mi=0; mi<4; mi++){
      float iv = 1.0f / rsum[nf*16 + lk*4 + mi];
      #pragma unroll
      for (int cf=0; cf<2; cf++)
        __builtin_nontemporal_store(tanh_fast(acc[nf][cf][mi]*iv),
                                    dst + (size_t)(nf*16 + lk*4 + mi)*ATTN + cf*16 + lrow);
    }

  // probs expansion (ch==0 only): wave w re-reads its 8 key-tiles (L2-hot), scales, NT f32
  if (ch == 0){
    float* prow = probs + ((size_t)b*SEQ + i0 + lrow)*SEQ + lk*8;
    #pragma unroll
    for (int nf=0; nf<4; nf++){
      float iv = 1.0f / rsum[nf*16 + lrow];
      #pragma unroll
      for (int k2=0; k2<8; k2++){
        int kt = w*8 + k2;
        f16x8 pa = *(const f16x8*)(pbase + (size_t)nf*32768 + kt*512);
        f32x4 lo = {(float)pa[0]*iv, (float)pa[1]*iv, (float)pa[2]*iv, (float)pa[3]*iv};
        f32x4 hi = {(float)pa[4]*iv, (float)pa[5]*iv, (float)pa[6]*iv, (float)pa[7]*iv};
        float* pr = prow + (size_t)nf*16*SEQ + kt*32;
        __builtin_nontemporal_store(lo, (f32x4*)(pr));
        __builtin_nontemporal_store(hi, (f32x4*)(pr + 4));
      }
    }
  }
}

// ---------------- K3 fallback: context = probs(f32) @ v ----------------
__global__ __launch_bounds__(512,4) void k_pv(const float* __restrict__ probs, const __half* __restrict__ vT,
                                              float* __restrict__ out0){
  int bid = blockIdx.x;
  int b  = bid & 7;
  int i0 = (bid >> 3) * 32;
  int t = threadIdx.x;
  int w = t >> 6, lane = t & 63;
  int lrow = lane & 15, lk = lane >> 4;
  int loff = lrow*32 + lk*8;

  const float* pbase = probs + ((size_t)b*SEQ + i0 + lrow)*SEQ + lk*8;
  const __half* vbase = vT + (size_t)b*ATTN*SEQ + (size_t)(w*4)*32768 + loff;

  f32x4 acc[2][4];
  #pragma unroll
  for (int i=0;i<2;i++)
    #pragma unroll
    for (int j=0;j<4;j++) acc[i][j] = f32x4{0.f,0.f,0.f,0.f};

  for (int kt = 0; kt < 64; kt++){
    int k0 = kt*32;
    f16x8 af[2];
    #pragma unroll
    for (int nf=0; nf<2; nf++){
      const float* pr = pbase + (size_t)nf*16*SEQ + k0;
      float4 a = *(const float4*)(pr);
      float4 c = *(const float4*)(pr + 4);
      f16x8 h;
      h[0]=(_Float16)a.x; h[1]=(_Float16)a.y; h[2]=(_Float16)a.z; h[3]=(_Float16)a.w;
      h[4]=(_Float16)c.x; h[5]=(_Float16)c.y; h[6]=(_Float16)c.z; h[7]=(_Float16)c.w;
      af[nf] = h;
    }
    #pragma unroll
    for (int cf=0; cf<4; cf++){
      f16x8 bv8 = *(const f16x8*)(vbase + (size_t)cf*32768 + kt*512);
      acc[0][cf] = __builtin_amdgcn_mfma_f32_16x16x32_f16(af[0], bv8, acc[0][cf], 0,0,0);
      acc[1][cf] = __builtin_amdgcn_mfma_f32_16x16x32_f16(af[1], bv8, acc[1][cf], 0,0,0);
    }
  }

  float* dst = out0 + ((size_t)b*SEQ + i0)*ATTN + w*64;
  #pragma unroll
  for (int nf=0; nf<2; nf++)
    #pragma unroll
    for (int cf=0; cf<4; cf++)
      #pragma unroll
      for (int mi=0; mi<4; mi++)
        dst[(size_t)(nf*16 + lk*4 + mi)*ATTN + cf*16 + lrow] = tanh_fast(acc[nf][cf][mi]);
}

extern "C" void kernel_launch(void* const* d_in, const int* in_sizes, int n_in,
                              void* d_out, int out_size, void* d_ws, size_t ws_size,
                              hipStream_t stream){
  const float* x  = (const float*)d_in[0];
  const float* Wq = (const float*)d_in[1];
  const float* bq = (const float*)d_in[2];
  const float* Wk = (const float*)d_in[3];
  const float* bk = (const float*)d_in[4];
  const float* Wv = (const float*)d_in[5];
  const float* bv = (const float*)d_in[6];

  float* out0 = (float*)d_out;                        // [8,2048,512]  tanh(context)   33.55 MB
  float* out1 = out0 + (size_t)NB*SEQ*ATTN;           // [8,2048,2048] probs          134.2 MB

  const size_t SZ = 16777216;                         // 16.78 MB
  char* ws = (char*)d_ws;

  if (ws_size >= 5*SZ){
    // MAIN path. ws: vT | p16(E, unnormalized). out1 scratch: xh | whT | qh | kh
    // (all dead before k_pv_p16 overwrites out1 with probs).
    __half* vT  = (__half*)ws;                           // 16.78 MB tiled (written by k_proj)
    __half* p16 = (__half*)(ws + SZ);                    // 67.1 MB tiled (unnormalized E)
    __half* xh  = (__half*)out1;                         // 33.55 MB
    __half* whT = (__half*)((char*)out1 + 2*SZ);         // 3.15 MB
    __half* qh  = (__half*)((char*)out1 + 2*SZ + 3145728);          // 16.78 MB tiled
    __half* kh  = (__half*)((char*)out1 + 3*SZ + 3145728);          // 16.78 MB tiled
    k_cast_x     <<<8192,        256, 0, stream>>>(x, xh);
    k_transpose_w<<<dim3(512,3), 256, 0, stream>>>(Wq, Wk, Wv, whT);
    k_proj       <<<dim3(12,128),256, 0, stream>>>(xh, whT, bq, bk, bv, qh, kh, vT);
    k_scoresE    <<<256,         512, 0, stream>>>(qh, kh, p16);
    k_pv_p16     <<<512,         512, 0, stream>>>(p16, vT, out1, out0);
  } else if (ws_size >= 3*SZ){
    // fallback: qh/kh in ws, normalized f32 probs path
    __half* vT = (__half*)ws;
    __half* qh = (__half*)(ws + SZ);
    __half* kh = (__half*)(ws + 2*SZ);
    __half* xh  = (__half*)out1;
    __half* whT = (__half*)((char*)out1 + 2*SZ);
    k_cast_x     <<<8192,        256, 0, stream>>>(x, xh);
    k_transpose_w<<<dim3(512,3), 256, 0, stream>>>(Wq, Wk, Wv, whT);
    k_proj       <<<dim3(12,128),256, 0, stream>>>(xh, whT, bq, bk, bv, qh, kh, vT);
    k_scores     <<<512,        1024, 0, stream>>>(qh, kh, out1);
    k_pv         <<<512,         512, 0, stream>>>(out1, vT, out0);
  } else {
    // minimal-ws fallback: qh/kh overlay out0
    __half* vT = (__half*)ws;
    __half* qh = (__half*)out0;
    __half* kh = (__half*)out0 + (size_t)MROWS*ATTN;
    __half* xh  = (__half*)out1;
    __half* whT = (__half*)((char*)out1 + 2*SZ);
    k_cast_x     <<<8192,        256, 0, stream>>>(x, xh);
    k_transpose_w<<<dim3(512,3), 256, 0, stream>>>(Wq, Wk, Wv, whT);
    k_proj       <<<dim3(12,128),256, 0, stream>>>(xh, whT, bq, bk, bv, qh, kh, vT);
    k_scores     <<<512,        1024, 0, stream>>>(qh, kh, out1);
    k_pv         <<<512,         512, 0, stream>>>(out1, vT, out0);
  }
}

// Round 17
// 265.774 us; speedup vs baseline: 1.1421x; 1.1421x over previous
//
#include <hip/hip_runtime.h>
#include <hip/hip_fp16.h>
#include <cstdint>

#define HIDDEN 1024
#define ATTN   512
#define NB     8
#define SEQ    2048
#define MROWS  (NB*SEQ)   // 16384

typedef _Float16 f16x8 __attribute__((ext_vector_type(8)));
typedef _Float16 f16x4 __attribute__((ext_vector_type(4)));
typedef float    f32x4 __attribute__((ext_vector_type(4)));

// Fragment-major tiled layout for all fp16 MFMA operands (q/k/vT/P16):
//   addr(r, c) = (r>>4)*(16*C) + (c>>5)*512 + (r&15)*32 + (c&31)   [halfs]
// => a wave's 16x32 fragment is one contiguous 1KB block (single-segment load).

__device__ __forceinline__ float tanh_fast(float x){
  float e = __expf(2.0f*x);
  return 1.0f - 2.0f/(e + 1.0f);
}

__device__ __forceinline__ void gload16(const void* g, void* l){
  __builtin_amdgcn_global_load_lds((const __attribute__((address_space(1))) void*)g,
                                   (__attribute__((address_space(3))) void*)l, 16, 0, 0);
}

// ---------------- K0a: cast inputs f32 -> fp16 ----------------
__global__ __launch_bounds__(256) void k_cast_x(const float* __restrict__ x, __half* __restrict__ xh){
  size_t i = (size_t)blockIdx.x*256 + threadIdx.x;
  const float4* src = reinterpret_cast<const float4*>(x) + i*2;
  float4 a = src[0], b = src[1];
  f16x8 h;
  h[0]=(_Float16)a.x; h[1]=(_Float16)a.y; h[2]=(_Float16)a.z; h[3]=(_Float16)a.w;
  h[4]=(_Float16)b.x; h[5]=(_Float16)b.y; h[6]=(_Float16)b.z; h[7]=(_Float16)b.w;
  reinterpret_cast<f16x8*>(xh)[i] = h;
}

// ---------------- K0b: W[1024][512] f32 -> WhT[512][1024] fp16 (x3) ----------------
__global__ __launch_bounds__(256) void k_transpose_w(const float* __restrict__ Wq, const float* __restrict__ Wk,
                                                     const float* __restrict__ Wv, __half* __restrict__ whT){
  __shared__ float lds[32][33];
  int which = blockIdx.y;
  const float* W = which==0 ? Wq : (which==1 ? Wk : Wv);
  int tr = blockIdx.x >> 4;
  int tc = blockIdx.x & 15;
  int t = threadIdx.x;
  {
    int r = t >> 3, c4 = (t & 7)*4;
    float4 v = *reinterpret_cast<const float4*>(W + (size_t)(tr*32 + r)*ATTN + tc*32 + c4);
    lds[r][c4+0]=v.x; lds[r][c4+1]=v.y; lds[r][c4+2]=v.z; lds[r][c4+3]=v.w;
  }
  __syncthreads();
  {
    int n = t >> 3, k4 = (t & 7)*4;
    ushort4 u;
    u.x = __half_as_ushort(__float2half(lds[k4+0][n]));
    u.y = __half_as_ushort(__float2half(lds[k4+1][n]));
    u.z = __half_as_ushort(__float2half(lds[k4+2][n]));
    u.w = __half_as_ushort(__float2half(lds[k4+3][n]));
    *reinterpret_cast<ushort4*>(whT + (size_t)which*ATTN*HIDDEN + (size_t)(tc*32 + n)*HIDDEN + tr*32 + k4) = u;
  }
}

// ---------------- K1: fused QKV projection ----------------
__global__ __launch_bounds__(256,3) void k_proj(const __half* __restrict__ xh, const __half* __restrict__ whT,
                                                const float* __restrict__ bq, const float* __restrict__ bk,
                                                const float* __restrict__ bv,
                                                __half* __restrict__ qh, __half* __restrict__ kh, __half* __restrict__ vT){
  __shared__ __align__(16) _Float16 lA[128*64];   // 16 KB
  __shared__ __align__(16) _Float16 lB[128*64];   // 16 KB
  int nt = blockIdx.x;             // 0..11 : which = nt>>2, 128-col slab = nt&3
  int m0 = blockIdx.y * 128;
  int which = nt >> 2;
  int ncol0 = (nt & 3) * 128;
  int t = threadIdx.x;
  int w = t >> 6, lane = t & 63;
  int lrow = lane & 15, lk = lane >> 4;
  int wm = w >> 1, wn = w & 1;

  int rr = lane >> 3;
  int ss = (lane & 7) ^ rr;
  const __half* Abase = xh + (size_t)(m0 + w*32 + rr)*HIDDEN + ss*8;
  const __half* Bbase = whT + (size_t)which*ATTN*HIDDEN + (size_t)(ncol0 + w*32 + rr)*HIDDEN + ss*8;
  _Float16* lAw = &lA[(w*32)*64];
  _Float16* lBw = &lB[(w*32)*64];

  f32x4 acc[4][4];
  #pragma unroll
  for (int i=0;i<4;i++)
    #pragma unroll
    for (int j=0;j<4;j++) acc[i][j] = f32x4{0.f,0.f,0.f,0.f};

  for (int k0 = 0; k0 < HIDDEN; k0 += 64){
    __syncthreads();
    #pragma unroll
    for (int c=0; c<4; c++){
      gload16(Abase + (size_t)c*8*HIDDEN + k0, &lAw[c*8*64]);
      gload16(Bbase + (size_t)c*8*HIDDEN + k0, &lBw[c*8*64]);
    }
    __syncthreads();
    #pragma unroll
    for (int u=0; u<2; u++){
      f16x8 af[4], bf[4];
      #pragma unroll
      for (int fm=0; fm<4; fm++){
        int row = wm*64 + fm*16 + lrow;
        af[fm] = *(const f16x8*)&lA[row*64 + (((u*4 + lk) ^ (row & 7))*8)];
      }
      #pragma unroll
      for (int fn=0; fn<4; fn++){
        int row = wn*64 + fn*16 + lrow;
        bf[fn] = *(const f16x8*)&lB[row*64 + (((u*4 + lk) ^ (row & 7))*8)];
      }
      #pragma unroll
      for (int fm=0; fm<4; fm++)
        #pragma unroll
        for (int fn=0; fn<4; fn++)
          acc[fm][fn] = __builtin_amdgcn_mfma_f32_16x16x32_f16(af[fm], bf[fn], acc[fm][fn], 0,0,0);
    }
  }

  const float* bias = which==0 ? bq : (which==1 ? bk : bv);
  if (which < 2){
    __half* dst = which==0 ? qh : kh;
    int rt_base = (m0 >> 4) + wm*4;
    int at_base = (ncol0 >> 5) + wn*2;
    #pragma unroll
    for (int fn=0; fn<4; fn++){
      int col = ncol0 + wn*64 + fn*16 + lrow;
      float bb = bias[col];
      int at = at_base + (fn >> 1);
      int asub = (fn & 1)*16 + lrow;
      #pragma unroll
      for (int fm=0; fm<4; fm++){
        size_t tbase = (size_t)(rt_base + fm)*8192 + (size_t)at*512 + asub;
        #pragma unroll
        for (int mi=0; mi<4; mi++)
          dst[tbase + (lk*4 + mi)*32] = __float2half(tanh_fast(acc[fm][fn][mi] + bb));
      }
    }
  } else {
    __half* vb = vT + (size_t)(m0 >> 11)*ATTN*SEQ;
    int jb0 = (m0 & 2047) + wm*64;
    int at0 = (ncol0 >> 4) + wn*4;
    #pragma unroll
    for (int fn=0; fn<4; fn++){
      int col = ncol0 + wn*64 + fn*16 + lrow;
      float bb = bias[col];
      #pragma unroll
      for (int fm=0; fm<4; fm++){
        int jb = jb0 + fm*16;
        f16x4 h;
        #pragma unroll
        for (int mi=0; mi<4; mi++) h[mi] = (_Float16)tanh_fast(acc[fm][fn][mi] + bb);
        *(f16x4*)(vb + (size_t)(at0 + fn)*32768 + (size_t)(jb >> 5)*512 + lrow*32 + (jb & 16) + lk*4) = h;
      }
    }
  }
}

// ---------------- K2: E = exp(QK^T * scale) UNNORMALIZED -> p16 (tiled) ----------------
// 256 blocks (1/CU), 512 thr. q (64 KB) staged once; kh double-width staged (64 KB =
// 2 dim-slices per barrier pair) -> 32 barrier pairs instead of 64.
__global__ __launch_bounds__(512,2) void k_scoresE(const __half* __restrict__ qh, const __half* __restrict__ kh,
                                                   __half* __restrict__ p16){
  __shared__ __align__(16) _Float16 qlds[4*16*512];    // 64 KB
  __shared__ __align__(16) _Float16 khlds[64*512];     // 64 KB: [slice 0|1][32 chunks]
  int bid = blockIdx.x;
  int b  = bid & 7;            // XCD pin
  int i0 = (bid >> 3) * 64;
  int t = threadIdx.x;
  int w = t >> 6, lane = t & 63;
  int lrow = lane & 15, lk = lane >> 4;

  const __half* qsrc = qh + (size_t)((b*SEQ + i0) >> 4)*8192;
  const __half* ksrc = kh + (size_t)b*SEQ*ATTN;
  __half* pb = p16 + (size_t)b*SEQ*SEQ;

  #pragma unroll
  for (int r=0; r<8; r++){
    int chunk = r*8 + w;
    gload16(qsrc + (size_t)chunk*512 + lane*8, &qlds[chunk*512]);
  }

  const float scale = 0.044194173824159216f;   // 1/sqrt(512)
  for (int ko = 0; ko < 4; ko++){
    f32x4 acc[4][4];
    #pragma unroll
    for (int i=0;i<4;i++)
      #pragma unroll
      for (int j=0;j<4;j++) acc[i][j] = f32x4{0.f,0.f,0.f,0.f};

    for (int it = 0; it < 16; it += 2){
      __syncthreads();
      #pragma unroll
      for (int j=0; j<4; j++){
        int c = w*4 + j;
        gload16(ksrc + (size_t)(ko*32 + c)*8192 + it*512 + lane*8,       &khlds[c*512]);
        gload16(ksrc + (size_t)(ko*32 + c)*8192 + (it+1)*512 + lane*8,   &khlds[(32 + c)*512]);
      }
      __syncthreads();
      #pragma unroll
      for (int half=0; half<2; half++){
        f16x8 kf[4], qf[4];
        #pragma unroll
        for (int j=0;j<4;j++) kf[j] = *(const f16x8*)&khlds[(half*32 + w*4+j)*512 + lrow*32 + lk*8];
        #pragma unroll
        for (int j=0;j<4;j++) qf[j] = *(const f16x8*)&qlds[(j*16 + it + half)*512 + lrow*32 + lk*8];
        #pragma unroll
        for (int fn=0; fn<4; fn++)
          #pragma unroll
          for (int qi=0; qi<4; qi++)
            acc[qi][fn] = __builtin_amdgcn_mfma_f32_16x16x32_f16(kf[fn], qf[qi], acc[qi][fn], 0,0,0);
      }
    }

    #pragma unroll
    for (int qi=0; qi<4; qi++){
      size_t tq = (size_t)((i0 >> 4) + qi)*32768;
      #pragma unroll
      for (int fn=0; fn<4; fn++){
        f16x4 h;
        #pragma unroll
        for (int mi=0; mi<4; mi++) h[mi] = (_Float16)__expf(acc[qi][fn][mi]*scale);
        *(f16x4*)&pb[tq + (size_t)(ko*16 + w*2 + (fn>>1))*512 + lrow*32 + (fn&1)*16 + lk*4] = h;
      }
    }
  }
}

// ---------------- K2b: expand E -> normalized f32 probs (coalesced) + row sums ----------------
// 1024 blocks (4/CU), 256 thr (4 waves). Block = one 16-row slab (64 KB contiguous p16).
// Stage slab linearly to LDS; compute 16 row sums (write rsumg for k_pv_p16);
// write probs with 1KB-per-instruction coalesced NT row stores (wave = one row).
__global__ __launch_bounds__(256,4) void k_expand(const __half* __restrict__ p16,
                                                  float* __restrict__ probs, float* __restrict__ rsumg){
  __shared__ __align__(16) _Float16 lds[16*2048];   // 64 KB
  __shared__ float partial[16][16];
  __shared__ float rs[16];
  int bid = blockIdx.x;
  int b  = bid & 7;            // XCD pin: slab written by this XCD's scoresE blocks
  int tq = bid >> 3;           // 0..127
  int t = threadIdx.x;
  int w = t >> 6, lane = t & 63;

  const __half* src = p16 + (size_t)b*SEQ*SEQ + (size_t)tq*32768;
  // stage 64 KB: 64 x 1KB chunks, wave w takes chunk i*4+w
  #pragma unroll
  for (int i=0; i<16; i++){
    int chunk = i*4 + w;
    gload16(src + (size_t)chunk*512 + lane*8, &lds[chunk*512]);
  }
  __syncthreads();

  // row sums: thread (r = t&15, seg = t>>4) sums keys [seg*128, +128) of row r
  {
    int r = t & 15, seg = t >> 4;
    float s = 0.f;
    #pragma unroll
    for (int c8=0; c8<16; c8++){
      int c = seg*128 + c8*8;
      f16x8 v = *(const f16x8*)&lds[(c >> 5)*512 + r*32 + (c & 31)];
      #pragma unroll
      for (int j=0;j<8;j++) s += (float)v[j];
    }
    partial[seg][r] = s;
  }
  __syncthreads();
  if (t < 16){
    float s = 0.f;
    #pragma unroll
    for (int seg=0; seg<16; seg++) s += partial[seg][t];
    rs[t] = s;
    rsumg[(size_t)b*SEQ + tq*16 + t] = s;
  }
  __syncthreads();

  // coalesced probs write: wave w owns rows {w, w+4, w+8, w+12}; per row 8 x 1KB NT stores
  float* pbase = probs + ((size_t)b*SEQ + tq*16)*SEQ;
  #pragma unroll
  for (int rr=0; rr<4; rr++){
    int r = rr*4 + w;
    float iv = 1.0f / rs[r];
    float* prow = pbase + (size_t)r*SEQ;
    #pragma unroll
    for (int ki=0; ki<8; ki++){
      int c = ki*256 + lane*4;
      f16x4 v = *(const f16x4*)&lds[(c >> 5)*512 + r*32 + (c & 31)];
      f32x4 o = {(float)v[0]*iv, (float)v[1]*iv, (float)v[2]*iv, (float)v[3]*iv};
      __builtin_nontemporal_store(o, (f32x4*)(prow + c));
    }
  }
}

// ---------------- K2 fallback: scores + no-max softmax (normalized f32 probs) ----------------
__global__ __launch_bounds__(1024,4) void k_scores(const __half* __restrict__ qh, const __half* __restrict__ kh,
                                                   float* __restrict__ probs){
  __shared__ float red[16][32];
  int bid = blockIdx.x;
  int b  = bid & 7;
  int i0 = (bid >> 3) * 32;
  int t = threadIdx.x;
  int w = t >> 6, lane = t & 63;
  int lrow = lane & 15, lk = lane >> 4;
  int loff = lrow*32 + lk*8;

  const __half* kbase = kh + (size_t)((b*SEQ + w*128) >> 4)*8192 + loff;
  const __half* qbase = qh + (size_t)((b*SEQ + i0) >> 4)*8192 + loff;

  f32x4 acc[2][8];
  #pragma unroll
  for (int i=0;i<2;i++)
    #pragma unroll
    for (int j=0;j<8;j++) acc[i][j] = f32x4{0.f,0.f,0.f,0.f};

  for (int it = 0; it < 16; it++){
    f16x8 aq0 = *(const f16x8*)(qbase + it*512);
    f16x8 aq1 = *(const f16x8*)(qbase + 8192 + it*512);
    #pragma unroll
    for (int fn=0; fn<8; fn++){
      f16x8 kf = *(const f16x8*)(kbase + (size_t)fn*8192 + it*512);
      acc[0][fn] = __builtin_amdgcn_mfma_f32_16x16x32_f16(kf, aq0, acc[0][fn], 0,0,0);
      acc[1][fn] = __builtin_amdgcn_mfma_f32_16x16x32_f16(kf, aq1, acc[1][fn], 0,0,0);
    }
  }

  const float scale = 0.044194173824159216f;
  float sm[2];
  #pragma unroll
  for (int nf=0;nf<2;nf++){
    float s = 0.f;
    #pragma unroll
    for (int fn=0;fn<8;fn++)
      #pragma unroll
      for (int mi=0;mi<4;mi++){
        float e = __expf(acc[nf][fn][mi] * scale);
        acc[nf][fn][mi] = e;
        s += e;
      }
    s += __shfl_xor(s, 16);
    s += __shfl_xor(s, 32);
    sm[nf] = s;
  }
  if (lane < 16){ red[w][lane] = sm[0]; red[w][16 + lane] = sm[1]; }
  __syncthreads();
  float inv[2];
  #pragma unroll
  for (int nf=0;nf<2;nf++){
    float tot = 0.f;
    #pragma unroll
    for (int ww=0; ww<16; ww++) tot += red[ww][nf*16 + lrow];
    inv[nf] = 1.0f / tot;
  }
  #pragma unroll
  for (int nf=0;nf<2;nf++){
    f32x4 iv = {inv[nf], inv[nf], inv[nf], inv[nf]};
    #pragma unroll
    for (int fn=0;fn<8;fn++){
      f32x4 v = acc[nf][fn] * iv;
      size_t rowoff = (size_t)(i0 + nf*16 + lrow)*SEQ + w*128 + lk*4;
      *(f32x4*)(probs + (size_t)b*SEQ*SEQ + rowoff + fn*16) = v;
    }
  }
}

// ---------------- K3main: context from E + rsumg (no probs, no esum) ----------------
// 256 blocks (1/CU), 512 thr (8 waves). Block: 64 q-rows x 512 cols; wave w: cols [w*64,+64).
// All loads contiguous 1KB fragments; out0 NT only.
__global__ __launch_bounds__(512,4) void k_pv_p16(const __half* __restrict__ p16, const __half* __restrict__ vT,
                                                  const float* __restrict__ rsumg, float* __restrict__ out0){
  int bid = blockIdx.x;
  int b  = bid & 7;            // XCD pin
  int i0 = (bid >> 3) * 64;
  int t = threadIdx.x;
  int w = t >> 6, lane = t & 63;
  int lrow = lane & 15, lk = lane >> 4;
  int loff = lrow*32 + lk*8;

  const __half* pbase = p16 + (size_t)b*SEQ*SEQ + (size_t)(i0 >> 4)*32768 + loff;
  const __half* vbase = vT + (size_t)b*ATTN*SEQ + (size_t)(w*4)*32768 + loff;

  f32x4 acc[4][4];
  #pragma unroll
  for (int i=0;i<4;i++)
    #pragma unroll
    for (int j=0;j<4;j++) acc[i][j] = f32x4{0.f,0.f,0.f,0.f};

  for (int kt = 0; kt < 64; kt++){
    f16x8 pa[4];
    #pragma unroll
    for (int nf=0; nf<4; nf++)
      pa[nf] = *(const f16x8*)(pbase + (size_t)nf*32768 + kt*512);
    #pragma unroll
    for (int cf=0; cf<4; cf++){
      f16x8 bv8 = *(const f16x8*)(vbase + (size_t)cf*32768 + kt*512);
      #pragma unroll
      for (int nf=0; nf<4; nf++)
        acc[nf][cf] = __builtin_amdgcn_mfma_f32_16x16x32_f16(pa[nf], bv8, acc[nf][cf], 0,0,0);
    }
  }

  float* dst = out0 + ((size_t)b*SEQ + i0)*ATTN + w*64;
  #pragma unroll
  for (int nf=0; nf<4; nf++){
    f32x4 rs4 = *(const f32x4*)&rsumg[(size_t)b*SEQ + i0 + nf*16 + lk*4];
    #pragma unroll
    for (int mi=0; mi<4; mi++){
      float iv = 1.0f / rs4[mi];
      #pragma unroll
      for (int cf=0; cf<4; cf++)
        __builtin_nontemporal_store(tanh_fast(acc[nf][cf][mi]*iv),
                                    dst + (size_t)(nf*16 + lk*4 + mi)*ATTN + cf*16 + lrow);
    }
  }
}

// ---------------- K3 fallback: context = probs(f32) @ v ----------------
__global__ __launch_bounds__(512,4) void k_pv(const float* __restrict__ probs, const __half* __restrict__ vT,
                                              float* __restrict__ out0){
  int bid = blockIdx.x;
  int b  = bid & 7;
  int i0 = (bid >> 3) * 32;
  int t = threadIdx.x;
  int w = t >> 6, lane = t & 63;
  int lrow = lane & 15, lk = lane >> 4;
  int loff = lrow*32 + lk*8;

  const float* pbase = probs + ((size_t)b*SEQ + i0 + lrow)*SEQ + lk*8;
  const __half* vbase = vT + (size_t)b*ATTN*SEQ + (size_t)(w*4)*32768 + loff;

  f32x4 acc[2][4];
  #pragma unroll
  for (int i=0;i<2;i++)
    #pragma unroll
    for (int j=0;j<4;j++) acc[i][j] = f32x4{0.f,0.f,0.f,0.f};

  for (int kt = 0; kt < 64; kt++){
    int k0 = kt*32;
    f16x8 af[2];
    #pragma unroll
    for (int nf=0; nf<2; nf++){
      const float* pr = pbase + (size_t)nf*16*SEQ + k0;
      float4 a = *(const float4*)(pr);
      float4 c = *(const float4*)(pr + 4);
      f16x8 h;
      h[0]=(_Float16)a.x; h[1]=(_Float16)a.y; h[2]=(_Float16)a.z; h[3]=(_Float16)a.w;
      h[4]=(_Float16)c.x; h[5]=(_Float16)c.y; h[6]=(_Float16)c.z; h[7]=(_Float16)c.w;
      af[nf] = h;
    }
    #pragma unroll
    for (int cf=0; cf<4; cf++){
      f16x8 bv8 = *(const f16x8*)(vbase + (size_t)cf*32768 + kt*512);
      acc[0][cf] = __builtin_amdgcn_mfma_f32_16x16x32_f16(af[0], bv8, acc[0][cf], 0,0,0);
      acc[1][cf] = __builtin_amdgcn_mfma_f32_16x16x32_f16(af[1], bv8, acc[1][cf], 0,0,0);
    }
  }

  float* dst = out0 + ((size_t)b*SEQ + i0)*ATTN + w*64;
  #pragma unroll
  for (int nf=0; nf<2; nf++)
    #pragma unroll
    for (int cf=0; cf<4; cf++)
      #pragma unroll
      for (int mi=0; mi<4; mi++)
        dst[(size_t)(nf*16 + lk*4 + mi)*ATTN + cf*16 + lrow] = tanh_fast(acc[nf][cf][mi]);
}

extern "C" void kernel_launch(void* const* d_in, const int* in_sizes, int n_in,
                              void* d_out, int out_size, void* d_ws, size_t ws_size,
                              hipStream_t stream){
  const float* x  = (const float*)d_in[0];
  const float* Wq = (const float*)d_in[1];
  const float* bq = (const float*)d_in[2];
  const float* Wk = (const float*)d_in[3];
  const float* bk = (const float*)d_in[4];
  const float* Wv = (const float*)d_in[5];
  const float* bv = (const float*)d_in[6];

  float* out0 = (float*)d_out;                        // [8,2048,512]  tanh(context)   33.55 MB
  float* out1 = out0 + (size_t)NB*SEQ*ATTN;           // [8,2048,2048] probs          134.2 MB

  const size_t SZ = 16777216;                         // 16.78 MB
  char* ws = (char*)d_ws;

  if (ws_size >= 5*SZ + 65536){
    // MAIN path. ws: vT | p16(E, unnormalized) | rsumg. out1 scratch: xh | whT | qh | kh.
    __half* vT    = (__half*)ws;                         // 16.78 MB tiled (written by k_proj)
    __half* p16   = (__half*)(ws + SZ);                  // 67.1 MB tiled (unnormalized E)
    float*  rsumg = (float*)(ws + 5*SZ);                 // 64 KB row sums
    __half* xh  = (__half*)out1;
    __half* whT = (__half*)((char*)out1 + 2*SZ);
    __half* qh  = (__half*)((char*)out1 + 2*SZ + 3145728);
    __half* kh  = (__half*)((char*)out1 + 3*SZ + 3145728);
    k_cast_x     <<<8192,        256, 0, stream>>>(x, xh);
    k_transpose_w<<<dim3(512,3), 256, 0, stream>>>(Wq, Wk, Wv, whT);
    k_proj       <<<dim3(12,128),256, 0, stream>>>(xh, whT, bq, bk, bv, qh, kh, vT);
    k_scoresE    <<<256,         512, 0, stream>>>(qh, kh, p16);
    k_expand     <<<1024,        256, 0, stream>>>(p16, out1, rsumg);
    k_pv_p16     <<<256,         512, 0, stream>>>(p16, vT, rsumg, out0);
  } else if (ws_size >= 3*SZ){
    // fallback: qh/kh in ws, normalized f32 probs path
    __half* vT = (__half*)ws;
    __half* qh = (__half*)(ws + SZ);
    __half* kh = (__half*)(ws + 2*SZ);
    __half* xh  = (__half*)out1;
    __half* whT = (__half*)((char*)out1 + 2*SZ);
    k_cast_x     <<<8192,        256, 0, stream>>>(x, xh);
    k_transpose_w<<<dim3(512,3), 256, 0, stream>>>(Wq, Wk, Wv, whT);
    k_proj       <<<dim3(12,128),256, 0, stream>>>(xh, whT, bq, bk, bv, qh, kh, vT);
    k_scores     <<<512,        1024, 0, stream>>>(qh, kh, out1);
    k_pv         <<<512,         512, 0, stream>>>(out1, vT, out0);
  } else {
    // minimal-ws fallback: qh/kh overlay out0
    __half* vT = (__half*)ws;
    __half* qh = (__half*)out0;
    __half* kh = (__half*)out0 + (size_t)MROWS*ATTN;
    __half* xh  = (__half*)out1;
    __half* whT = (__half*)((char*)out1 + 2*SZ);
    k_cast_x     <<<8192,        256, 0, stream>>>(x, xh);
    k_transpose_w<<<dim3(512,3), 256, 0, stream>>>(Wq, Wk, Wv, whT);
    k_proj       <<<dim3(12,128),256, 0, stream>>>(xh, whT, bq, bk, bv, qh, kh, vT);
    k_scores     <<<512,        1024, 0, stream>>>(qh, kh, out1);
    k_pv         <<<512,         512, 0, stream>>>(out1, vT, out0);
  }
}